// Round 1
// baseline (713.437 us; speedup 1.0000x reference)
//
#include <hip/hip_runtime.h>
#include <hip/hip_bf16.h>

#define T_SEQ 2048
#define NH 8
#define CD 64
#define QT 64
#define SB 64
#define LDP 72   // padded LDS row stride in bf16 elems (144 B, 16B-aligned)

typedef __bf16 bf16x8 __attribute__((ext_vector_type(8)));
typedef unsigned short ushort8v __attribute__((ext_vector_type(8)));
typedef float f32x4 __attribute__((ext_vector_type(4)));

__device__ __forceinline__ unsigned short f2bf(float x) {
    __hip_bfloat16 b = __float2bfloat16(x);
    return __builtin_bit_cast(unsigned short, b);
}

__device__ __forceinline__ bf16x8 ld_frag(const unsigned short* p) {
    ushort8v v = *reinterpret_cast<const ushort8v*>(p);
    return __builtin_bit_cast(bf16x8, v);
}

__global__ __launch_bounds__(256, 1)
void qkv_attn_kernel(const float* __restrict__ qkv, float* __restrict__ out) {
    __shared__ __align__(16) unsigned short Qs[QT][LDP];   // Qs[t][c]
    __shared__ __align__(16) unsigned short Ks[SB][LDP];   // Ks[s][c] (transposed)
    __shared__ __align__(16) unsigned short Vs[CD][LDP];   // Vs[c][s] (natural)
    __shared__ __align__(16) unsigned short Ps[4*16][LDP]; // Ps[wave*16 + t][s]
    __shared__ __align__(16) float Ot[4][CD][17];          // per-wave transpose buf

    const int tid  = threadIdx.x;
    const int wave = tid >> 6;
    const int lane = tid & 63;
    const int g    = lane >> 4;   // 16-lane group
    const int p    = lane & 15;

    const int t0 = blockIdx.x * QT;
    const int bh = blockIdx.y;          // 0..31
    const int b  = bh >> 3;
    const int h  = bh & 7;

    const size_t Tl = T_SEQ;
    const float* qg = qkv + ((size_t)b * (3 * NH * CD) + (size_t)h * CD) * Tl;
    const float* kg = qg + (size_t)NH * CD * Tl;       // +512*T
    const float* vg = qg + (size_t)2 * NH * CD * Tl;   // +1024*T

    // ---- stage Q tile once: Qs[t][c] (transpose of global [c][t]) ----
    #pragma unroll
    for (int i = 0; i < 16; ++i) {
        int idx = tid + i * 256;       // 0..4095
        int c   = idx >> 6;            // 0..63
        int tl  = idx & 63;
        Qs[tl][c] = f2bf(qg[(size_t)c * Tl + t0 + tl]);
    }

    const float s2 = 1.0f / (float)T_SEQ;  // (1/sqrt(T))^2 applied to logits

    float m_run[4], l_run[4];
    f32x4 Oacc[4];
    #pragma unroll
    for (int r = 0; r < 4; ++r) {
        m_run[r] = -1e30f;
        l_run[r] = 0.0f;
        Oacc[r]  = f32x4{0.f, 0.f, 0.f, 0.f};
    }

    for (int s0 = 0; s0 < T_SEQ; s0 += SB) {
        __syncthreads();   // prev iter's K/V reads done (also covers Q staging)
        // ---- stage K (transposed) and V (natural) ----
        #pragma unroll
        for (int i = 0; i < 16; ++i) {
            int idx = tid + i * 256;
            int c   = idx >> 6;
            int sl  = idx & 63;
            Ks[sl][c] = f2bf(kg[(size_t)c * Tl + s0 + sl]);
            Vs[c][sl] = f2bf(vg[(size_t)c * Tl + s0 + sl]);
        }
        __syncthreads();

        // ---- QK^T: wave's 16 t-rows x 64 s-cols ----
        f32x4 S[4];
        #pragma unroll
        for (int ci = 0; ci < 4; ++ci) {
            S[ci] = f32x4{0.f, 0.f, 0.f, 0.f};
            #pragma unroll
            for (int ks = 0; ks < 2; ++ks) {
                bf16x8 a  = ld_frag(&Qs[wave * 16 + p][ks * 32 + 8 * g]);
                bf16x8 bb = ld_frag(&Ks[ci * 16 + p][ks * 32 + 8 * g]);
                S[ci] = __builtin_amdgcn_mfma_f32_16x16x32_bf16(a, bb, S[ci], 0, 0, 0);
            }
        }

        // ---- online softmax. D layout: row=(g*4+r), col=(p+16*ci) ----
        float mnew[4], alpha[4], rsum[4];
        #pragma unroll
        for (int r = 0; r < 4; ++r) {
            float mx = -1e30f;
            #pragma unroll
            for (int ci = 0; ci < 4; ++ci) mx = fmaxf(mx, S[ci][r]);
            mx *= s2;   // s2 > 0: scaling commutes with max
            #pragma unroll
            for (int off = 1; off < 16; off <<= 1) mx = fmaxf(mx, __shfl_xor(mx, off));
            float mn = fmaxf(m_run[r], mx);
            mnew[r]  = mn;
            alpha[r] = __expf(m_run[r] - mn);
            m_run[r] = mn;
            rsum[r]  = 0.f;
        }
        #pragma unroll
        for (int ci = 0; ci < 4; ++ci) {
            #pragma unroll
            for (int r = 0; r < 4; ++r) {
                float pv = __expf(S[ci][r] * s2 - mnew[r]);
                rsum[r] += pv;
                Ps[wave * 16 + g * 4 + r][ci * 16 + p] = f2bf(pv);
            }
        }
        #pragma unroll
        for (int r = 0; r < 4; ++r) {
            float rs = rsum[r];
            #pragma unroll
            for (int off = 1; off < 16; off <<= 1) rs += __shfl_xor(rs, off);
            l_run[r] = l_run[r] * alpha[r] + rs;
        }

        // ---- PV: O[t][c] += P[t][s] * V^T[s][c] ----
        bf16x8 pa[2];
        #pragma unroll
        for (int ks = 0; ks < 2; ++ks)
            pa[ks] = ld_frag(&Ps[wave * 16 + p][ks * 32 + 8 * g]);
        #pragma unroll
        for (int cb = 0; cb < 4; ++cb) {
            f32x4 o = Oacc[cb];
            #pragma unroll
            for (int r = 0; r < 4; ++r) o[r] *= alpha[r];
            #pragma unroll
            for (int ks = 0; ks < 2; ++ks) {
                bf16x8 bv = ld_frag(&Vs[cb * 16 + p][ks * 32 + 8 * g]);
                o = __builtin_amdgcn_mfma_f32_16x16x32_bf16(pa[ks], bv, o, 0, 0, 0);
            }
            Oacc[cb] = o;
        }
    }

    // ---- epilogue: normalize, transpose via LDS (per-wave), coalesced store ----
    #pragma unroll
    for (int cb = 0; cb < 4; ++cb)
        #pragma unroll
        for (int r = 0; r < 4; ++r)
            Ot[wave][cb * 16 + p][g * 4 + r] = Oacc[cb][r] / l_run[r];

    // within-wave LDS exchange; compiler inserts lgkmcnt waits
    const float* orow = &Ot[wave][lane][0];
    float* op = out + ((size_t)bh * CD + lane) * Tl + t0 + wave * 16;
    #pragma unroll
    for (int t = 0; t < 16; ++t) op[t] = orow[t];
}

extern "C" void kernel_launch(void* const* d_in, const int* in_sizes, int n_in,
                              void* d_out, int out_size, void* d_ws, size_t ws_size,
                              hipStream_t stream) {
    const float* qkv = (const float*)d_in[0];
    float* out = (float*)d_out;
    dim3 grid(T_SEQ / QT, 4 * NH);   // (t-tiles, B*H)
    qkv_attn_kernel<<<grid, 256, 0, stream>>>(qkv, out);
}

// Round 2
// 95.125 us; speedup vs baseline: 7.5000x; 7.5000x over previous
//
#include <hip/hip_runtime.h>
#include <hip/hip_bf16.h>

#define T_SEQ 2048
#define NH    8
#define CD    64
#define QT    64
#define SB    64
#define LDP   72
#define NSTEP (T_SEQ / SB)

typedef __bf16 bf16x8 __attribute__((ext_vector_type(8)));
typedef unsigned short ushort8v __attribute__((ext_vector_type(8)));
typedef unsigned short ushort4v __attribute__((ext_vector_type(4)));
typedef float f32x4 __attribute__((ext_vector_type(4)));

__device__ __forceinline__ unsigned short f2bf(float x) {
    __hip_bfloat16 b = __float2bfloat16(x);
    return __builtin_bit_cast(unsigned short, b);
}

__device__ __forceinline__ bf16x8 ld_frag(const unsigned short* p) {
    return __builtin_bit_cast(bf16x8, *reinterpret_cast<const ushort8v*>(p));
}

__device__ __forceinline__ f32x4 mfma16(bf16x8 a, bf16x8 b, f32x4 c) {
    return __builtin_amdgcn_mfma_f32_16x16x32_bf16(a, b, c, 0, 0, 0);
}

__global__ __launch_bounds__(256, 4)
void qkv_attn_kernel(const float* __restrict__ qkv, float* __restrict__ out) {
    // Q,K,V,P tiles each [64][LDP] bf16 = 9216 B -> 36864 B total -> 4 blocks/CU
    __shared__ __align__(16) unsigned short smem[4 * 64 * LDP];
    unsigned short (*Qs)[LDP] = (unsigned short (*)[LDP])(smem);
    unsigned short (*Ks)[LDP] = (unsigned short (*)[LDP])(smem + 64 * LDP);
    unsigned short (*Vs)[LDP] = (unsigned short (*)[LDP])(smem + 2 * 64 * LDP);
    unsigned short (*Ps)[LDP] = (unsigned short (*)[LDP])(smem + 3 * 64 * LDP);

    const int tid  = threadIdx.x;
    const int wave = tid >> 6;
    const int lane = tid & 63;
    const int g    = lane >> 4;   // 16-lane group
    const int p    = lane & 15;

    // staging decomposition: tq = t/s quad (fixed per thread), c0 = base channel
    const int tq  = tid & 15;
    const int c0  = tid >> 4;          // +16*i, i=0..3
    const int rot = (tq & 7) << 3;     // rotation for transposed staging rows (row>>2 == tq)

    const int t0 = blockIdx.x * QT;
    const int bh = blockIdx.y;          // 0..31
    const int b  = bh >> 3;
    const int h  = bh & 7;

    const size_t Tl = T_SEQ;
    const float* qg = qkv + ((size_t)b * (3 * NH * CD) + (size_t)h * CD) * Tl;
    const float* kg = qg + (size_t)NH * CD * Tl;
    const float* vg = qg + (size_t)2 * NH * CD * Tl;

    // ---- prologue: issue Q + first K/V loads, stage Q (scaled by log2e/T) ----
    f32x4 kreg[4], vreg[4];
    {
        f32x4 qreg[4];
        #pragma unroll
        for (int i = 0; i < 4; ++i)
            qreg[i] = *(const f32x4*)(qg + (size_t)(c0 + 16 * i) * Tl + t0 + tq * 4);
        #pragma unroll
        for (int i = 0; i < 4; ++i) {
            kreg[i] = *(const f32x4*)(kg + (size_t)(c0 + 16 * i) * Tl + tq * 4);
            vreg[i] = *(const f32x4*)(vg + (size_t)(c0 + 16 * i) * Tl + tq * 4);
        }
        const float qsc = 1.4426950408889634f / (float)T_SEQ; // log2e * (1/sqrt(T))^2
        #pragma unroll
        for (int i = 0; i < 4; ++i) {
            int col = ((c0 + 16 * i) + rot) & 63;
            #pragma unroll
            for (int j = 0; j < 4; ++j)
                Qs[tq * 4 + j][col] = f2bf(qreg[i][j] * qsc);
        }
    }

    const int rotRow = (4 * wave + (p >> 2)) & 7;  // rotation selector for row wave*16+p

    float lpart[4];
    f32x4 Oacc[4];
    #pragma unroll
    for (int r = 0; r < 4; ++r) { lpart[r] = 0.f; Oacc[r] = f32x4{0.f, 0.f, 0.f, 0.f}; }

    for (int it = 0; it < NSTEP; ++it) {
        __syncthreads();   // all waves done reading previous K/V tile (also covers Q stage)
        // ---- write staged regs -> LDS ----
        #pragma unroll
        for (int i = 0; i < 4; ++i) {
            int col = ((c0 + 16 * i) + rot) & 63;
            #pragma unroll
            for (int j = 0; j < 4; ++j)
                Ks[tq * 4 + j][col] = f2bf(kreg[i][j]);   // transposed + rotated
            ushort4v pk;
            #pragma unroll
            for (int j = 0; j < 4; ++j) pk[j] = f2bf(vreg[i][j]);
            *reinterpret_cast<ushort4v*>(&Vs[c0 + 16 * i][tq * 4]) = pk;  // natural
        }
        // ---- issue next tile's loads (overlap with compute below) ----
        if (it + 1 < NSTEP) {
            const int s0n = (it + 1) * SB;
            #pragma unroll
            for (int i = 0; i < 4; ++i) {
                kreg[i] = *(const f32x4*)(kg + (size_t)(c0 + 16 * i) * Tl + s0n + tq * 4);
                vreg[i] = *(const f32x4*)(vg + (size_t)(c0 + 16 * i) * Tl + s0n + tq * 4);
            }
        }
        __syncthreads();   // staging visible

        // ---- QK^T ----
        f32x4 S[4];
        #pragma unroll
        for (int ci = 0; ci < 4; ++ci) S[ci] = f32x4{0.f, 0.f, 0.f, 0.f};
        #pragma unroll
        for (int ks = 0; ks < 2; ++ks) {
            bf16x8 a = ld_frag(&Qs[wave * 16 + p][((4 * ks + g + rotRow) & 7) << 3]);
            #pragma unroll
            for (int ci = 0; ci < 4; ++ci) {
                int rotB = (4 * ci + (p >> 2)) & 7;
                bf16x8 bb = ld_frag(&Ks[ci * 16 + p][((4 * ks + g + rotB) & 7) << 3]);
                S[ci] = mfma16(a, bb, S[ci]);
            }
        }

        // ---- softmax: P = exp2(S) (Q pre-scaled; logits tiny -> no max needed) ----
        const int rotPW = ((4 * wave + g) & 7) << 3;
        #pragma unroll
        for (int ci = 0; ci < 4; ++ci) {
            int colP = (16 * ci + p + rotPW) & 63;
            #pragma unroll
            for (int r = 0; r < 4; ++r) {
                float e = __builtin_amdgcn_exp2f(S[ci][r]);
                lpart[r] += e;
                Ps[wave * 16 + g * 4 + r][colP] = f2bf(e);
            }
        }

        // ---- PV ----
        bf16x8 pa0 = ld_frag(&Ps[wave * 16 + p][((0 + g + rotRow) & 7) << 3]);
        bf16x8 pa1 = ld_frag(&Ps[wave * 16 + p][((4 + g + rotRow) & 7) << 3]);
        #pragma unroll
        for (int cb = 0; cb < 4; ++cb) {
            Oacc[cb] = mfma16(pa0, ld_frag(&Vs[cb * 16 + p][8 * g]), Oacc[cb]);
            Oacc[cb] = mfma16(pa1, ld_frag(&Vs[cb * 16 + p][32 + 8 * g]), Oacc[cb]);
        }
    }

    // ---- final l reduction (deferred across all steps) ----
    #pragma unroll
    for (int r = 0; r < 4; ++r) {
        float l = lpart[r];
        l += __shfl_xor(l, 1);
        l += __shfl_xor(l, 2);
        l += __shfl_xor(l, 4);
        l += __shfl_xor(l, 8);
        lpart[r] = 1.0f / l;
    }

    // ---- epilogue: transpose via LDS overlay (per-wave slice), coalesced store ----
    __syncthreads();   // everyone done with K/V/Q tiles before overlay
    float (*Ot)[20] = (float (*)[20])((char*)smem + (size_t)wave * (64 * 20 * 4));
    #pragma unroll
    for (int cb = 0; cb < 4; ++cb)
        #pragma unroll
        for (int r = 0; r < 4; ++r)
            Ot[cb * 16 + p][g * 4 + r] = Oacc[cb][r] * lpart[r];

    float* op = out + ((size_t)bh * CD + lane) * Tl + t0 + wave * 16;
    const float* orow = Ot[lane];
    #pragma unroll
    for (int jj = 0; jj < 4; ++jj)
        *reinterpret_cast<f32x4*>(op + jj * 4) = *reinterpret_cast<const f32x4*>(orow + jj * 4);
}

extern "C" void kernel_launch(void* const* d_in, const int* in_sizes, int n_in,
                              void* d_out, int out_size, void* d_ws, size_t ws_size,
                              hipStream_t stream) {
    const float* qkv = (const float*)d_in[0];
    float* out = (float*)d_out;
    dim3 grid(T_SEQ / QT, 4 * NH);
    qkv_attn_kernel<<<grid, 256, 0, stream>>>(qkv, out);
}

// Round 3
// 88.921 us; speedup vs baseline: 8.0232x; 1.0698x over previous
//
#include <hip/hip_runtime.h>
#include <hip/hip_bf16.h>

#define T_SEQ 2048
#define NH    8
#define CD    64
#define QT    64
#define SB    64
#define NSTEP (T_SEQ / SB)

// LDS element map (bf16 elems):
//   Qpan: [4][64][16] @ 0      (panel tp = t>>4, row c, minor t&15)   8 KB
//   Kpan: [4][64][16] @ 4096   (panel ci = s>>4, row c, minor s&15)   8 KB
//   Vnat: [64][72]    @ 8192   (row c, s contiguous, padded)          9 KB
//   Ppan: [4][64][16] @ 12800  (panel = wave, row s, minor t&15)      8 KB
#define KPAN_E 4096
#define VNAT_E 8192
#define PPAN_E 12800
#define SMEM_E 16896

typedef __bf16 bf16x8 __attribute__((ext_vector_type(8)));
typedef unsigned short ushort8v __attribute__((ext_vector_type(8)));
typedef unsigned short ushort4v __attribute__((ext_vector_type(4)));
typedef unsigned int u32x2 __attribute__((ext_vector_type(2)));
typedef unsigned int u32x4 __attribute__((ext_vector_type(4)));
typedef float f32x4 __attribute__((ext_vector_type(4)));

__device__ __forceinline__ unsigned short f2bf(float x) {
    __hip_bfloat16 b = __float2bfloat16(x);
    return __builtin_bit_cast(unsigned short, b);
}

__device__ __forceinline__ bf16x8 ld_frag(const unsigned short* ptr) {
    return __builtin_bit_cast(bf16x8, *reinterpret_cast<const ushort8v*>(ptr));
}

__device__ __forceinline__ bf16x8 cat(u32x2 a, u32x2 b) {
    u32x4 t; t[0] = a[0]; t[1] = a[1]; t[2] = b[0]; t[3] = b[1];
    return __builtin_bit_cast(bf16x8, t);
}

__device__ __forceinline__ f32x4 mfma16(bf16x8 a, bf16x8 b, f32x4 c) {
    return __builtin_amdgcn_mfma_f32_16x16x32_bf16(a, b, c, 0, 0, 0);
}

// ds_read_b64_tr_b16: lane reads 4 bf16 at elem-stride 16 (32B) from its own addr.
#define TRRD(dst, addr, off) \
    asm volatile("ds_read_b64_tr_b16 %0, %1 offset:%2" : "=v"(dst) : "v"(addr), "i"(off))

__global__ __launch_bounds__(256, 4)
void qkv_attn_kernel(const float* __restrict__ qkv, float* __restrict__ out) {
    __shared__ __align__(16) unsigned short smem[SMEM_E];

    const int tid  = threadIdx.x;
    const int wave = tid >> 6;
    const int lane = tid & 63;
    const int g    = lane >> 4;
    const int p    = lane & 15;

    // staging decomposition: cb = c base (0..15, +16*i), sq = s/t quad (0..15)
    const int cb = tid >> 4;
    const int sq = tid & 15;

    const int t0 = blockIdx.x * QT;
    const int bh = blockIdx.y;
    const int b  = bh >> 3;
    const int h  = bh & 7;

    const size_t Tl = T_SEQ;
    const float* qg = qkv + ((size_t)b * (3 * NH * CD) + (size_t)h * CD) * Tl;
    const float* kg = qg + (size_t)NH * CD * Tl;
    const float* vg = qg + (size_t)2 * NH * CD * Tl;

    // per-lane tr-read base addrs (bytes; loop-invariant)
    const unsigned lds0  = (unsigned)(uintptr_t)smem;
    const unsigned qaddr = lds0 + (unsigned)(wave * 2048 + g * 256 + 2 * p);
    const unsigned kaddr = lds0 + (unsigned)(2 * KPAN_E + g * 256 + 2 * p);
    const unsigned paddr = lds0 + (unsigned)(2 * PPAN_E + wave * 2048 + g * 256 + 2 * p);

    // ---- prologue: load Q + first K/V, stage Q panels (scaled by log2e/T) ----
    f32x4 kreg[4], vreg[4];
    {
        f32x4 qreg[4];
        #pragma unroll
        for (int i = 0; i < 4; ++i)
            qreg[i] = *(const f32x4*)(qg + (size_t)(cb + 16 * i) * Tl + t0 + sq * 4);
        #pragma unroll
        for (int i = 0; i < 4; ++i) {
            kreg[i] = *(const f32x4*)(kg + (size_t)(cb + 16 * i) * Tl + sq * 4);
            vreg[i] = *(const f32x4*)(vg + (size_t)(cb + 16 * i) * Tl + sq * 4);
        }
        const float qsc = 1.4426950408889634f / (float)T_SEQ; // log2e * (1/sqrt(T))^2
        #pragma unroll
        for (int i = 0; i < 4; ++i) {
            const int c = cb + 16 * i;
            ushort4v q4;
            #pragma unroll
            for (int j = 0; j < 4; ++j) q4[j] = f2bf(qreg[i][j] * qsc);
            *reinterpret_cast<ushort4v*>(&smem[(sq >> 2) * 1024 + c * 16 + (sq & 3) * 4]) = q4;
        }
    }
    __syncthreads();

    // ---- hoist Q A-fragments (same every step) ----
    bf16x8 qa0, qa1;
    {
        u32x2 qr[4];
        TRRD(qr[0], qaddr, 0);
        TRRD(qr[1], qaddr, 128);
        TRRD(qr[2], qaddr, 1024);
        TRRD(qr[3], qaddr, 1152);
        asm volatile("s_waitcnt lgkmcnt(0)");
        __builtin_amdgcn_sched_barrier(0);
        qa0 = cat(qr[0], qr[1]);
        qa1 = cat(qr[2], qr[3]);
    }

    float lpart[4];
    f32x4 Oacc[4];
    #pragma unroll
    for (int r = 0; r < 4; ++r) { lpart[r] = 0.f; Oacc[r] = f32x4{0.f, 0.f, 0.f, 0.f}; }

    for (int it = 0; it < NSTEP; ++it) {
        __syncthreads();   // all waves done reading previous K/V tile (iter0: Q-frag reads done)
        // ---- staged regs -> LDS (packed 8B writes, natural orientation) ----
        #pragma unroll
        for (int i = 0; i < 4; ++i) {
            const int c = cb + 16 * i;
            ushort4v k4, v4;
            #pragma unroll
            for (int j = 0; j < 4; ++j) { k4[j] = f2bf(kreg[i][j]); v4[j] = f2bf(vreg[i][j]); }
            *reinterpret_cast<ushort4v*>(&smem[KPAN_E + (sq >> 2) * 1024 + c * 16 + (sq & 3) * 4]) = k4;
            *reinterpret_cast<ushort4v*>(&smem[VNAT_E + c * 72 + sq * 4]) = v4;
        }
        // ---- issue next tile's global loads (hide under compute) ----
        if (it + 1 < NSTEP) {
            const int s0n = (it + 1) * SB;
            #pragma unroll
            for (int i = 0; i < 4; ++i) {
                kreg[i] = *(const f32x4*)(kg + (size_t)(cb + 16 * i) * Tl + s0n + sq * 4);
                vreg[i] = *(const f32x4*)(vg + (size_t)(cb + 16 * i) * Tl + s0n + sq * 4);
            }
        }
        __syncthreads();

        // ---- QK^T: 16 tr-reads -> wait -> 8 MFMA ----
        u32x2 kr[16];
        #define KRD(ci, ks, sel) TRRD(kr[(ci)*4 + (ks)*2 + (sel)], kaddr, (ci)*2048 + (ks)*1024 + (sel)*128)
        KRD(0,0,0); KRD(0,0,1); KRD(0,1,0); KRD(0,1,1);
        KRD(1,0,0); KRD(1,0,1); KRD(1,1,0); KRD(1,1,1);
        KRD(2,0,0); KRD(2,0,1); KRD(2,1,0); KRD(2,1,1);
        KRD(3,0,0); KRD(3,0,1); KRD(3,1,0); KRD(3,1,1);
        #undef KRD
        asm volatile("s_waitcnt lgkmcnt(0)");
        __builtin_amdgcn_sched_barrier(0);
        f32x4 S[4];
        #pragma unroll
        for (int ci = 0; ci < 4; ++ci) {
            S[ci] = f32x4{0.f, 0.f, 0.f, 0.f};
            S[ci] = mfma16(qa0, cat(kr[ci * 4 + 0], kr[ci * 4 + 1]), S[ci]);
            S[ci] = mfma16(qa1, cat(kr[ci * 4 + 2], kr[ci * 4 + 3]), S[ci]);
        }

        // ---- softmax: P = exp2(S); packed transposed store into P panel ----
        #pragma unroll
        for (int ci = 0; ci < 4; ++ci) {
            ushort4v p4;
            #pragma unroll
            for (int r = 0; r < 4; ++r) {
                float e = __builtin_amdgcn_exp2f(S[ci][r]);
                lpart[r] += e;
                p4[r] = f2bf(e);
            }
            *reinterpret_cast<ushort4v*>(&smem[PPAN_E + wave * 1024 + (16 * ci + p) * 16 + 4 * g]) = p4;
        }
        asm volatile("" ::: "memory");  // compiler fence: P writes before tr-reads (HW DS queue is in-order per wave)

        // ---- PV: 4 P tr-reads + 8 V b128 reads -> 8 MFMA ----
        u32x2 pr[4];
        TRRD(pr[0], paddr, 0);
        TRRD(pr[1], paddr, 128);
        TRRD(pr[2], paddr, 1024);
        TRRD(pr[3], paddr, 1152);
        asm volatile("s_waitcnt lgkmcnt(0)");
        __builtin_amdgcn_sched_barrier(0);
        bf16x8 pa0 = cat(pr[0], pr[1]);
        bf16x8 pa1 = cat(pr[2], pr[3]);
        #pragma unroll
        for (int cb2 = 0; cb2 < 4; ++cb2) {
            Oacc[cb2] = mfma16(pa0, ld_frag(&smem[VNAT_E + (cb2 * 16 + p) * 72 + 8 * g]), Oacc[cb2]);
            Oacc[cb2] = mfma16(pa1, ld_frag(&smem[VNAT_E + (cb2 * 16 + p) * 72 + 32 + 8 * g]), Oacc[cb2]);
        }
    }

    // ---- final l reduction (deferred across all steps) ----
    #pragma unroll
    for (int r = 0; r < 4; ++r) {
        float l = lpart[r];
        l += __shfl_xor(l, 1);
        l += __shfl_xor(l, 2);
        l += __shfl_xor(l, 4);
        l += __shfl_xor(l, 8);
        lpart[r] = 1.0f / l;
    }

    // ---- epilogue: transpose via LDS overlay (per-wave slice), coalesced store ----
    __syncthreads();
    float (*Ot)[20] = (float (*)[20])((char*)smem + (size_t)wave * (64 * 20 * 4));
    #pragma unroll
    for (int cb2 = 0; cb2 < 4; ++cb2)
        #pragma unroll
        for (int r = 0; r < 4; ++r)
            Ot[cb2 * 16 + p][g * 4 + r] = Oacc[cb2][r] * lpart[r];

    float* op = out + ((size_t)bh * CD + lane) * Tl + t0 + wave * 16;
    const float* orow = Ot[lane];
    #pragma unroll
    for (int jj = 0; jj < 4; ++jj)
        *reinterpret_cast<f32x4*>(op + jj * 4) = *reinterpret_cast<const f32x4*>(orow + jj * 4);
}

extern "C" void kernel_launch(void* const* d_in, const int* in_sizes, int n_in,
                              void* d_out, int out_size, void* d_ws, size_t ws_size,
                              hipStream_t stream) {
    const float* qkv = (const float*)d_in[0];
    float* out = (float*)d_out;
    dim3 grid(T_SEQ / QT, 4 * NH);
    qkv_attn_kernel<<<grid, 256, 0, stream>>>(qkv, out);
}

// Round 4
// 58.328 us; speedup vs baseline: 12.2315x; 1.5245x over previous
//
#include <hip/hip_runtime.h>
#include <hip/hip_bf16.h>

#define T_SEQ 2048
#define NH    8
#define BH    32
#define CD    64
#define QT    128
#define SB    64
#define NSTEP (T_SEQ / SB)

typedef __bf16 bf16x8 __attribute__((ext_vector_type(8)));
typedef float f32x4 __attribute__((ext_vector_type(4)));
typedef float f32x16 __attribute__((ext_vector_type(16)));
typedef unsigned int u32x4 __attribute__((ext_vector_type(4)));
typedef unsigned short ushort4v __attribute__((ext_vector_type(4)));

__device__ __forceinline__ unsigned short f2bf(float x) {
    __hip_bfloat16 b = __float2bfloat16(x);
    return __builtin_bit_cast(unsigned short, b);
}

__device__ __forceinline__ unsigned cvtpk(float lo, float hi) {
    unsigned r;
    asm("v_cvt_pk_bf16_f32 %0, %1, %2" : "=v"(r) : "v"(lo), "v"(hi));
    return r;
}

__device__ __forceinline__ void plswap(unsigned &a, unsigned &b) {
    asm("v_permlane32_swap_b32 %0, %1" : "+v"(a), "+v"(b));
}

__device__ __forceinline__ f32x16 mfma32(bf16x8 a, bf16x8 b, f32x16 c) {
    return __builtin_amdgcn_mfma_f32_32x32x16_bf16(a, b, c, 0, 0, 0);
}

// Build PV B-fragment for kstep: elems s = 16*ks + 8*hi + {0..7}.
// PP = exp2(S) regs of the owning sblk; B = 8*(ks&1).
// low4 from hi0-owner regs B..B+3, high4 from hi1-owner regs B..B+3 -> permlane32_swap.
#define BUILD_FRAG(PP, B, OUTFRAG) do {                      \
    unsigned w0 = cvtpk((PP)[(B)+0], (PP)[(B)+1]);           \
    unsigned w1 = cvtpk((PP)[(B)+2], (PP)[(B)+3]);           \
    unsigned w2 = cvtpk((PP)[(B)+4], (PP)[(B)+5]);           \
    unsigned w3 = cvtpk((PP)[(B)+6], (PP)[(B)+7]);           \
    plswap(w0, w2); plswap(w1, w3);                          \
    u32x4 t_; t_[0] = w0; t_[1] = w1; t_[2] = w2; t_[3] = w3;\
    OUTFRAG = __builtin_bit_cast(bf16x8, t_);                \
} while (0)

// ---------------- pre-pass: Q,K f32 [c][t] -> bf16 [t][c] (Q scaled by log2e/T) ----------------
__global__ __launch_bounds__(256, 4)
void prepass_qk(const float* __restrict__ qkv, unsigned short* __restrict__ dst) {
    __shared__ __align__(16) unsigned short Lt[64][72];
    const int tid = threadIdx.x;
    const int tt = blockIdx.x;       // 64-wide t tile
    const int bh = blockIdx.y;
    const int which = blockIdx.z;    // 0=Q, 1=K
    const int b = bh >> 3, h = bh & 7;
    const float scale = (which == 0) ? (1.4426950408889634f / 2048.0f) : 1.0f;
    const float* src = qkv + ((size_t)b * 1536 + which * 512 + h * 64) * 2048;

    const int cb = tid >> 4, tq = tid & 15;
    #pragma unroll
    for (int i = 0; i < 4; ++i) {
        const int c = cb + 16 * i;
        f32x4 v = *(const f32x4*)(src + (size_t)c * 2048 + tt * 64 + tq * 4);
        #pragma unroll
        for (int j = 0; j < 4; ++j)
            Lt[tq * 4 + j][c] = f2bf(v[j] * scale);
    }
    __syncthreads();
    const int r = tid >> 2, seg = tid & 3;
    unsigned short* o = dst + ((size_t)which * BH + bh) * (size_t)(T_SEQ * CD)
                      + (size_t)(tt * 64 + r) * 64 + seg * 16;
    *(u32x4*)(o)     = *(const u32x4*)((const char*)&Lt[r][0] + seg * 32);
    *(u32x4*)(o + 8) = *(const u32x4*)((const char*)&Lt[r][0] + seg * 32 + 16);
}

// ---------------- main attention ----------------
__global__ __launch_bounds__(256, 2)
void attn_main(const float* __restrict__ qkv, const unsigned short* __restrict__ qkbf,
               float* __restrict__ out) {
    // K tile [64][64] + V tile [64][64], bf16, XOR-swizzled (16B slot ^= row&7)
    __shared__ __align__(16) unsigned short smem[8192];
    unsigned short* smK = smem;
    unsigned short* smV = smem + 4096;

    const int tid  = threadIdx.x;
    const int wave = tid >> 6;
    const int lane = tid & 63;
    const int l31  = lane & 31;
    const int hi   = lane >> 5;
    const int r7   = l31 & 7;

    const int t0 = blockIdx.x * QT;
    const int bh = blockIdx.y;
    const int b  = bh >> 3, h = bh & 7;

    const float* vg = qkv + ((size_t)b * 1536 + 1024 + h * 64) * 2048;
    const unsigned short* qbf = qkbf + (size_t)bh * (T_SEQ * CD);
    const unsigned short* kbf = qkbf + (size_t)(BH + bh) * (T_SEQ * CD);

    // staging decomposition
    const int kr = tid >> 2, kseg = tid & 3;   // K: row s, 16-elem c-seg
    const int cbv = tid >> 4, sqv = tid & 15;  // V: c-base, s-quad

    // ---- Q fragments (hoisted; lane owns q = t0 + wave*32 + l31) ----
    bf16x8 qfrag[4];
    {
        const unsigned short* qrow = qbf + (size_t)(t0 + wave * 32 + l31) * 64 + hi * 8;
        #pragma unroll
        for (int ks = 0; ks < 4; ++ks)
            qfrag[ks] = __builtin_bit_cast(bf16x8, *(const u32x4*)(qrow + ks * 16));
    }

    // ---- initial prefetch ----
    u32x4 kpre[2];
    f32x4 vpre[4];
    #pragma unroll
    for (int bb = 0; bb < 2; ++bb)
        kpre[bb] = *(const u32x4*)(kbf + (size_t)kr * 64 + kseg * 16 + bb * 8);
    #pragma unroll
    for (int i = 0; i < 4; ++i)
        vpre[i] = *(const f32x4*)(vg + (size_t)(cbv + 16 * i) * 2048 + sqv * 4);

    f32x16 Oacc0 = {}, Oacc1 = {};
    float lp0 = 0.f, lp1 = 0.f;

    for (int it = 0; it < NSTEP; ++it) {
        __syncthreads();
        // ---- staged regs -> LDS (swizzled, conflict-free) ----
        #pragma unroll
        for (int bb = 0; bb < 2; ++bb)
            *(u32x4*)((char*)smK + kr * 128 + 16 * (((kseg << 1) | bb) ^ (kr & 7))) = kpre[bb];
        #pragma unroll
        for (int i = 0; i < 4; ++i) {
            const int c = cbv + 16 * i;
            ushort4v v4;
            #pragma unroll
            for (int j = 0; j < 4; ++j) v4[j] = f2bf(vpre[i][j]);
            *(ushort4v*)((char*)smV + c * 128 + ((8 * sqv) ^ ((c & 7) << 4))) = v4;
        }
        // ---- issue next tile's loads ----
        if (it + 1 < NSTEP) {
            const int s0n = (it + 1) * SB;
            #pragma unroll
            for (int bb = 0; bb < 2; ++bb)
                kpre[bb] = *(const u32x4*)(kbf + (size_t)(s0n + kr) * 64 + kseg * 16 + bb * 8);
            #pragma unroll
            for (int i = 0; i < 4; ++i)
                vpre[i] = *(const f32x4*)(vg + (size_t)(cbv + 16 * i) * 2048 + s0n + sqv * 4);
        }
        __syncthreads();

        // ---- swapped QK^T: S^T[s][q], lane owns q=l31, regs span s ----
        f32x16 S0 = {}, S1 = {};
        #pragma unroll
        for (int ks = 0; ks < 4; ++ks) {
            bf16x8 k0 = __builtin_bit_cast(bf16x8,
                *(const u32x4*)((char*)smK + l31 * 128        + 16 * (((ks << 1) | hi) ^ r7)));
            bf16x8 k1 = __builtin_bit_cast(bf16x8,
                *(const u32x4*)((char*)smK + (32 + l31) * 128 + 16 * (((ks << 1) | hi) ^ r7)));
            S0 = mfma32(k0, qfrag[ks], S0);
            S1 = mfma32(k1, qfrag[ks], S1);
        }

        // ---- P = exp2(S) in place; accumulate l ----
        #pragma unroll
        for (int i = 0; i < 16; ++i) {
            S0[i] = __builtin_amdgcn_exp2f(S0[i]);
            S1[i] = __builtin_amdgcn_exp2f(S1[i]);
            lp0 += S0[i];
            lp1 += S1[i];
        }

        // ---- PV: O^T[c][q] += V[c][s-slice] * P[q][s-slice] ----
        #pragma unroll
        for (int ks = 0; ks < 4; ++ks) {
            bf16x8 pf;
            if      (ks == 0) BUILD_FRAG(S0, 0, pf);
            else if (ks == 1) BUILD_FRAG(S0, 8, pf);
            else if (ks == 2) BUILD_FRAG(S1, 0, pf);
            else              BUILD_FRAG(S1, 8, pf);
            bf16x8 v0 = __builtin_bit_cast(bf16x8,
                *(const u32x4*)((char*)smV + l31 * 128        + 16 * (((ks << 1) | hi) ^ r7)));
            bf16x8 v1 = __builtin_bit_cast(bf16x8,
                *(const u32x4*)((char*)smV + (32 + l31) * 128 + 16 * (((ks << 1) | hi) ^ r7)));
            Oacc0 = mfma32(v0, pf, Oacc0);
            Oacc1 = mfma32(v1, pf, Oacc1);
        }
    }

    // ---- finish: lane owns q; partner lane (l^32) holds complementary s-half ----
    float lpart = lp0 + lp1;
    float lsum = lpart + __shfl_xor(lpart, 32);
    float rl = 1.0f / lsum;

    float* obase = out + (size_t)bh * 64 * 2048 + t0 + wave * 32 + l31;
    #pragma unroll
    for (int reg = 0; reg < 16; ++reg) {
        const int crow = (reg & 3) + 8 * (reg >> 2) + 4 * hi;
        obase[(size_t)crow * 2048]        = Oacc0[reg] * rl;
        obase[(size_t)(32 + crow) * 2048] = Oacc1[reg] * rl;
    }
}

extern "C" void kernel_launch(void* const* d_in, const int* in_sizes, int n_in,
                              void* d_out, int out_size, void* d_ws, size_t ws_size,
                              hipStream_t stream) {
    const float* qkv = (const float*)d_in[0];
    float* out = (float*)d_out;
    unsigned short* qkbf = (unsigned short*)d_ws;   // Q: 8 MB, K: 8 MB

    dim3 pgrid(T_SEQ / 64, BH, 2);
    prepass_qk<<<pgrid, 256, 0, stream>>>(qkv, qkbf);

    dim3 mgrid(T_SEQ / QT, BH);
    attn_main<<<mgrid, 256, 0, stream>>>(qkv, qkbf, out);
}